// Round 7
// baseline (73.810 us; speedup 1.0000x reference)
//
#include <hip/hip_runtime.h>
#include <math.h>

#define B_    32
#define C_    64
#define T_    512
#define NROWS (B_ * C_)
#define CMAX_ 16
#define FEPS  1.1920929e-07f
#define W2PI  0.012271846303085130f   // 2*pi/512

__device__ __forceinline__ float gelu_exact(float x) {
    return 0.5f * x * (1.0f + erff(x * 0.7071067811865475f));
}

// ---------------- mono kernel: DFT + top-3 + fold/conv/pools/seq ----------
// One row per block, 128 threads (2 waves). Wave w owns freqs
// f = 1 + tid + 128q (q=0,1); cross-wave top-3 merge in LDS.
__global__ __launch_bounds__(128) void mono_kernel(
    const float* __restrict__ feat,
    const float* __restrict__ w0, const float* __restrict__ b0,
    const float* __restrict__ w1, const float* __restrict__ b1,
    const float* __restrict__ w2, const float* __restrict__ b2,
    const float* __restrict__ wpj, const float* __restrict__ bpj,
    const float* __restrict__ wr, const float* __restrict__ br,
    float* __restrict__ avg_out, float* __restrict__ max_out,
    float* __restrict__ seq_out)
{
    __shared__ float rowp[520];          // rowp[2+i] = row[i]; halo 2 low / 6 high
    __shared__ __align__(16) float2 sds[256];
    __shared__ float WeffS[80];
    __shared__ float wtopS[6];
    __shared__ int   itopS[6];
    __shared__ int   ipS[9];             // P[3], cyc[3], base[3]
    __shared__ float bwS[3];

    const int tid = threadIdx.x;         // 0..127
    const int r = blockIdx.x;

    // ---- stage row into padded LDS ----
    {
        float4 v = reinterpret_cast<const float4*>(feat + (size_t)r * T_)[tid];
        int bi = 2 + tid * 4;
        rowp[bi + 0] = v.x; rowp[bi + 1] = v.y;
        rowp[bi + 2] = v.z; rowp[bi + 3] = v.w;
    }
    if (tid < 80) {
        int i = tid;
        if (i < 75) {
            int k = i / 25, ij = i % 25, ii = ij / 5, jj = ij % 5;
            float w = wpj[2] * w2[k * 25 + ii * 5 + jj];
            if (ii >= 1 && ii <= 3 && jj >= 1 && jj <= 3)
                w += wpj[1] * w1[k * 9 + (ii - 1) * 3 + (jj - 1)];
            if (ii == 2 && jj == 2) w += wpj[0] * w0[k];
            WeffS[i] = w;
        } else if (i == 75) {
            WeffS[75] = wpj[0] * b0[0] + wpj[1] * b1[0] + wpj[2] * b2[0] + bpj[0];
        } else if (i <= 78) {
            WeffS[i] = wr[i - 76];
        } else {
            WeffS[79] = br[0];
        }
    }
    __syncthreads();

    // ---- halo fill + symmetric/antisymmetric fold ----
    if (tid == 0) { float e = rowp[2]; rowp[0] = e; rowp[1] = e; }
    else if (tid == 1) {
        float e = rowp[513];
        rowp[514] = e; rowp[515] = e; rowp[516] = e;
        rowp[517] = e; rowp[518] = e; rowp[519] = e;
    }
    #pragma unroll
    for (int i = tid; i < 256; i += 128) {
        if (i == 255) sds[255] = make_float2(rowp[258], 0.0f);   // t=256 self-pair
        else          sds[i] = make_float2(rowp[3 + i] + rowp[513 - i],
                                           rowp[3 + i] - rowp[513 - i]);
    }
    __syncthreads();

    // ---- DFT: 2 freqs/thread, 4 rotation chains each, float4 sd reads ----
    float chc[2][4], chs[2][4], cS[2], sS[2], re[2], im[2];
    #pragma unroll
    for (int q = 0; q < 2; ++q) {
        const int fq = 1 + tid + 128 * q;
        const int a4 = (4 * fq) & 511;
        sincosf((float)a4 * W2PI, &sS[q], &cS[q]);
        #pragma unroll
        for (int j = 0; j < 4; ++j) {
            const int ph = (fq * (1 + j)) & 511;
            sincosf((float)ph * W2PI, &chs[q][j], &chc[q][j]);
        }
        re[q] = 0.f; im[q] = 0.f;
    }
    {
        const float4* s4 = reinterpret_cast<const float4*>(sds);
        #pragma unroll 2
        for (int g = 0; g < 64; ++g) {
            const float4 q0 = s4[2 * g];
            const float4 q1 = s4[2 * g + 1];
            const float ex[4] = {q0.x, q0.z, q1.x, q1.z};
            const float ey[4] = {q0.y, q0.w, q1.y, q1.w};
            #pragma unroll
            for (int q = 0; q < 2; ++q) {
                #pragma unroll
                for (int j = 0; j < 4; ++j) {
                    re[q] = fmaf(ex[j], chc[q][j], re[q]);
                    im[q] = fmaf(ey[j], chs[q][j], im[q]);
                    float cn = fmaf(-chs[q][j], sS[q], chc[q][j] * cS[q]);
                    float sn = fmaf( chc[q][j], sS[q], chs[q][j] * cS[q]);
                    chc[q][j] = cn; chs[q][j] = sn;
                }
            }
        }
    }
    const float x0 = rowp[2];
    float v[2]; int id[2];
    #pragma unroll
    for (int q = 0; q < 2; ++q) {
        float rr = re[q] + x0;
        v[q] = sqrtf(rr * rr + im[q] * im[q]);
        id[q] = 1 + tid + 128 * q;
    }

    // ---- wave-local top-3 then cross-wave merge ----
    {
        const int wv = tid >> 6;
        float vals[3]; int idxs[3];
        #pragma unroll
        for (int kk = 0; kk < 3; ++kk) {
            float bv = v[0]; int bi = id[0];
            if (v[1] > bv) { bv = v[1]; bi = id[1]; }
            #pragma unroll
            for (int off = 32; off >= 1; off >>= 1) {
                float ov = __shfl_xor(bv, off, 64);
                int   oi = __shfl_xor(bi, off, 64);
                if (ov > bv || (ov == bv && oi < bi)) { bv = ov; bi = oi; }
            }
            vals[kk] = bv; idxs[kk] = bi;
            #pragma unroll
            for (int q = 0; q < 2; ++q)
                if (id[q] == bi) v[q] = -1e30f;
        }
        if ((tid & 63) == 0) {
            #pragma unroll
            for (int kk = 0; kk < 3; ++kk) {
                wtopS[wv * 3 + kk] = vals[kk];
                itopS[wv * 3 + kk] = idxs[kk];
            }
        }
    }
    __syncthreads();
    if (tid == 0) {
        float vv[6]; int ii[6];
        #pragma unroll
        for (int q = 0; q < 6; ++q) { vv[q] = wtopS[q]; ii[q] = itopS[q]; }
        float vals[3]; int idxs[3];
        #pragma unroll
        for (int kk = 0; kk < 3; ++kk) {
            float bv = vv[0]; int bi = ii[0];
            #pragma unroll
            for (int q = 1; q < 6; ++q)
                if (vv[q] > bv || (vv[q] == bv && ii[q] < bi)) { bv = vv[q]; bi = ii[q]; }
            vals[kk] = bv; idxs[kk] = bi;
            #pragma unroll
            for (int q = 0; q < 6; ++q)
                if (ii[q] == bi) vv[q] = -1e30f;
        }
        float m = fmaxf(vals[0], fmaxf(vals[1], vals[2]));
        float e0 = expf(vals[0] - m), e1 = expf(vals[1] - m), e2 = expf(vals[2] - m);
        float inv = 1.0f / (e0 + e1 + e2);
        bwS[0] = e0 * inv; bwS[1] = e1 * inv; bwS[2] = e2 * inv;
        #pragma unroll
        for (int kk = 0; kk < 3; ++kk) {
            int fi = idxs[kk];
            int P = T_ / fi;
            P = P < 32 ? 32 : (P > 512 ? 512 : P);
            int cyc = T_ / P;
            ipS[kk] = P; ipS[3 + kk] = cyc; ipS[6 + kk] = T_ - cyc * P;
        }
    }
    __syncthreads();

    // ---- fold + conv + pools + seq ----
    const int P0  = __builtin_amdgcn_readfirstlane(ipS[0]);
    const int P1  = __builtin_amdgcn_readfirstlane(ipS[1]);
    const int P2  = __builtin_amdgcn_readfirstlane(ipS[2]);
    const int cy0 = __builtin_amdgcn_readfirstlane(ipS[3]);
    const int cy1 = __builtin_amdgcn_readfirstlane(ipS[4]);
    const int cy2 = __builtin_amdgcn_readfirstlane(ipS[5]);
    const int bs0 = __builtin_amdgcn_readfirstlane(ipS[6]);
    const int bs1 = __builtin_amdgcn_readfirstlane(ipS[7]);
    const int bs2 = __builtin_amdgcn_readfirstlane(ipS[8]);
    const float bw0 = bwS[0], bw1 = bwS[1], bw2 = bwS[2];
    const float beff = WeffS[75], wr0 = WeffS[76], wr1 = WeffS[77],
                wr2 = WeffS[78], bres = WeffS[79];

    int maxP = P0 > P1 ? P0 : P1; maxP = maxP > P2 ? maxP : P2;
    const int Pk[3]   = {P0, P1, P2};
    const int cykA[3] = {cy0, cy1, cy2};
    const int bskA[3] = {bs0, bs1, bs2};
    const int woff = tid & 64;          // wave base within chunk

    #pragma unroll 1
    for (int pc = 0; pc < T_; pc += 128) {
        const int p = pc + tid;
        const int wb = __builtin_amdgcn_readfirstlane(pc + woff);
        if (wb >= maxP) {
            avg_out[r * T_ + p] = 0.f;
            max_out[r * T_ + p] = 0.f;
            seq_out[r * T_ + p] = 0.f;
            continue;
        }
        int c0 = (P0 > wb) ? cy0 : 0;
        int c1 = (P1 > wb) ? cy1 : 0;
        int c2 = (P2 > wb) ? cy2 : 0;
        int cymax = c0 > c1 ? c0 : c1; cymax = cymax > c2 ? cymax : c2;
        cymax = __builtin_amdgcn_readfirstlane(cymax);

        float zacc[CMAX_];
        #pragma unroll
        for (int i = 0; i < CMAX_; ++i) zacc[i] = beff;

        #pragma unroll 1
        for (int k = 0; k < 3; ++k) {
            const int P = Pk[k];
            if (wb >= P) continue;          // wave-uniform skip
            const int cy = cykA[k];
            const int bs = bskA[k];
            float Wk[5][5];
            #pragma unroll
            for (int i = 0; i < 5; ++i)
                #pragma unroll
                for (int j = 0; j < 5; ++j)
                    Wk[i][j] = WeffS[k * 25 + i * 5 + j];
            bool mdw[5];
            #pragma unroll
            for (int dw = -2; dw <= 2; ++dw)
                mdw[dw + 2] = ((unsigned)(p + dw) < (unsigned)P);
            const int abase = bs + p + 2;   // padded-index base
            #pragma unroll
            for (int hh = 0; hh < CMAX_; ++hh) {
                if (hh < cy) {              // lane-uniform guard
                    const int a0 = abase + hh * P;
                    float w[5];
                    #pragma unroll
                    for (int dw = -2; dw <= 2; ++dw) {
                        unsigned a = (unsigned)(a0 + dw);
                        a = a > 517u ? 517u : a;    // single clamp (halo handles low)
                        float t = rowp[a];
                        w[dw + 2] = mdw[dw + 2] ? t : 0.f;
                    }
                    #pragma unroll
                    for (int dh = -2; dh <= 2; ++dh) {
                        const int cc = hh - dh;     // compile-time
                        if (cc >= 0 && cc < CMAX_) {
                            #pragma unroll
                            for (int dw = 0; dw < 5; ++dw)
                                zacc[cc] = fmaf(Wk[dh + 2][dw], w[dw], zacc[cc]);
                        }
                    }
                }
            }
        }

        float avg_num = 0.f, den = 0.f, mx = -3.402823466e38f;
        int anyv = 0;
        const int pl0 = (p < P0), pl1 = (p < P1), pl2 = (p < P2);
        #pragma unroll
        for (int cc = 0; cc < CMAX_; ++cc) {
            if (cc < cymax) {               // uniform guard
                int m0 = (cc < cy0) & pl0;
                int m1 = (cc < cy1) & pl1;
                int m2 = (cc < cy2) & pl2;
                unsigned a0 = (unsigned)(bs0 + cc * P0 + p); a0 = a0 > 511u ? 511u : a0;
                unsigned a1 = (unsigned)(bs1 + cc * P1 + p); a1 = a1 > 511u ? 511u : a1;
                unsigned a2 = (unsigned)(bs2 + cc * P2 + p); a2 = a2 > 511u ? 511u : a2;
                float x0v = m0 ? rowp[2 + a0] : 0.f;
                float x1v = m1 ? rowp[2 + a1] : 0.f;
                float x2v = m2 ? rowp[2 + a2] : 0.f;
                float res = fmaf(wr0, x0v, fmaf(wr1, x1v, fmaf(wr2, x2v, bres)));
                float z = gelu_exact(zacc[cc]) + res;
                int mm = m0 | m1 | m2;
                float cm = mm ? 1.f : 0.f;
                avg_num += z * cm;
                den += cm;
                mx = mm ? fmaxf(mx, z) : mx;
                anyv |= mm;
            }
        }
        float avg = avg_num / (den + FEPS);
        float mpool = anyv ? mx : 0.f;

        float seq = 0.f;
        #pragma unroll 1
        for (int k = 0; k < 3; ++k) {
            const int P = Pk[k];
            if (wb >= P) continue;
            const int cy = cykA[k];
            const int bs = bskA[k];
            float s = 0.f;
            for (int c2i = 0; c2i < cy; ++c2i) {
                unsigned a = (unsigned)(bs + c2i * P + p); a = a > 511u ? 511u : a;
                s += ((p < P) ? rowp[2 + a] : 0.f);
            }
            float brk = (p < P) ? s / ((float)cy + FEPS) : 0.f;
            float bwk = (k == 0) ? bw0 : (k == 1 ? bw1 : bw2);
            seq = fmaf(bwk, brk, seq);
        }

        avg_out[r * T_ + p] = avg;
        max_out[r * T_ + p] = mpool;
        seq_out[r * T_ + p] = seq;
    }
}

// ---------- fuse GEMM + gelu ----------
// grid (8 t-tiles, 32 b), 256 threads, 64o x 64t tile, 4x4 micro.
__global__ __launch_bounds__(256) void fuse_kernel(
    const float* __restrict__ avgb, const float* __restrict__ maxb,
    const float* __restrict__ seqb,
    const float* __restrict__ wf, const float* __restrict__ bfu,
    float* __restrict__ out)
{
    __shared__ float wT[64][68];    // wT[c][o]
    __shared__ float Bt[64][68];    // Bt[c][t]
    const int tid = threadIdx.x;
    const int b = blockIdx.y;
    const int tt0 = blockIdx.x * 64;
    const int og = tid >> 4;
    const int tg = tid & 15;
    const int o0 = og * 4;
    const int t0 = tg * 4;

    float acc[4][4];
    #pragma unroll
    for (int i = 0; i < 4; ++i)
        #pragma unroll
        for (int j = 0; j < 4; ++j) acc[i][j] = 0.f;

    const float* srcs[3] = {avgb, maxb, seqb};
    for (int g = 0; g < 3; ++g) {
        const float* __restrict__ src = srcs[g];
        #pragma unroll
        for (int it = 0; it < 4; ++it) {
            int idx = tid + it * 256;
            int c = idx >> 4, t4 = idx & 15;
            float4 vv = reinterpret_cast<const float4*>(
                            &src[(b * 64 + c) * 512 + tt0])[t4];
            *reinterpret_cast<float4*>(&Bt[c][t4 * 4]) = vv;
        }
        for (int i = tid; i < 64 * 64; i += 256) {
            int c = i & 63, o = i >> 6;
            wT[c][o] = wf[o * 192 + g * 64 + c];
        }
        __syncthreads();
        for (int c = 0; c < 64; ++c) {
            float4 wv = *reinterpret_cast<const float4*>(&wT[c][o0]);
            float4 bv = *reinterpret_cast<const float4*>(&Bt[c][t0]);
            const float wa[4] = {wv.x, wv.y, wv.z, wv.w};
            const float ba[4] = {bv.x, bv.y, bv.z, bv.w};
            #pragma unroll
            for (int i = 0; i < 4; ++i)
                #pragma unroll
                for (int j = 0; j < 4; ++j)
                    acc[i][j] = fmaf(wa[i], ba[j], acc[i][j]);
        }
        __syncthreads();
    }
    #pragma unroll
    for (int i = 0; i < 4; ++i) {
        float bias = bfu[o0 + i];
        float4 o4;
        o4.x = gelu_exact(acc[i][0] + bias);
        o4.y = gelu_exact(acc[i][1] + bias);
        o4.z = gelu_exact(acc[i][2] + bias);
        o4.w = gelu_exact(acc[i][3] + bias);
        *reinterpret_cast<float4*>(
            &out[(b * 64 + (o0 + i)) * 512 + tt0 + t0]) = o4;
    }
}

extern "C" void kernel_launch(void* const* d_in, const int* in_sizes, int n_in,
                              void* d_out, int out_size, void* d_ws, size_t ws_size,
                              hipStream_t stream) {
    const float* feat = (const float*)d_in[0];
    const float* w0  = (const float*)d_in[1];
    const float* b0  = (const float*)d_in[2];
    const float* w1  = (const float*)d_in[3];
    const float* b1  = (const float*)d_in[4];
    const float* w2  = (const float*)d_in[5];
    const float* b2  = (const float*)d_in[6];
    const float* wpj = (const float*)d_in[7];
    const float* bpj = (const float*)d_in[8];
    const float* wr  = (const float*)d_in[9];
    const float* br  = (const float*)d_in[10];
    const float* wf  = (const float*)d_in[11];
    const float* bfu = (const float*)d_in[12];

    float* ws = (float*)d_ws;
    float* avgb = ws;
    float* maxb = ws + (size_t)NROWS * T_;
    float* seqb = ws + 2 * (size_t)NROWS * T_;

    mono_kernel<<<NROWS, 128, 0, stream>>>(feat, w0, b0, w1, b1, w2, b2,
                                           wpj, bpj, wr, br, avgb, maxb, seqb);
    fuse_kernel<<<dim3(8, 32), 256, 0, stream>>>(avgb, maxb, seqb, wf, bfu,
                                                 (float*)d_out);
}

// Round 8
// 50.791 us; speedup vs baseline: 1.4532x; 1.4532x over previous
//
#include <hip/hip_runtime.h>
#include <math.h>

#define B_    32
#define C_    64
#define T_    512
#define NROWS (B_ * C_)
#define CMAX_ 16
#define FEPS  1.1920929e-07f
#define PI_F  3.14159265358979323846f

__device__ __forceinline__ float gelu_exact(float x) {
    return 0.5f * x * (1.0f + erff(x * 0.7071067811865475f));
}

// ---------------- mono kernel: rFFT + top-3 + fold/conv/pools/seq ----------
// One row per block, 128 threads (2 waves).
__global__ __launch_bounds__(128) void mono_kernel(
    const float* __restrict__ feat,
    const float* __restrict__ w0, const float* __restrict__ b0,
    const float* __restrict__ w1, const float* __restrict__ b1,
    const float* __restrict__ w2, const float* __restrict__ b2,
    const float* __restrict__ wpj, const float* __restrict__ bpj,
    const float* __restrict__ wr, const float* __restrict__ br,
    float* __restrict__ avg_out, float* __restrict__ max_out,
    float* __restrict__ seq_out)
{
    __shared__ float rowp[520];          // rowp[2+i] = row[i]; halo 2 low / 6 high
    __shared__ __align__(16) float2 FA[256];
    __shared__ __align__(16) float2 FB[256];
    __shared__ float WeffS[80];
    __shared__ float wtopS[6];
    __shared__ int   itopS[6];
    __shared__ int   ipS[9];             // P[3], cyc[3], base[3]
    __shared__ float bwS[3];

    const int tid = threadIdx.x;         // 0..127
    const int r = blockIdx.x;

    // ---- stage row into padded LDS ----
    {
        float4 v = reinterpret_cast<const float4*>(feat + (size_t)r * T_)[tid];
        int bi = 2 + tid * 4;
        rowp[bi + 0] = v.x; rowp[bi + 1] = v.y;
        rowp[bi + 2] = v.z; rowp[bi + 3] = v.w;
    }
    if (tid < 80) {
        int i = tid;
        if (i < 75) {
            int k = i / 25, ij = i % 25, ii = ij / 5, jj = ij % 5;
            float w = wpj[2] * w2[k * 25 + ii * 5 + jj];
            if (ii >= 1 && ii <= 3 && jj >= 1 && jj <= 3)
                w += wpj[1] * w1[k * 9 + (ii - 1) * 3 + (jj - 1)];
            if (ii == 2 && jj == 2) w += wpj[0] * w0[k];
            WeffS[i] = w;
        } else if (i == 75) {
            WeffS[75] = wpj[0] * b0[0] + wpj[1] * b1[0] + wpj[2] * b2[0] + bpj[0];
        } else if (i <= 78) {
            WeffS[i] = wr[i - 76];
        } else {
            WeffS[79] = br[0];
        }
    }
    __syncthreads();

    // ---- halo fill + pack reals into 256 complex: z[n] = x[2n] + i x[2n+1] ----
    if (tid == 0) { float e = rowp[2]; rowp[0] = e; rowp[1] = e; }
    else if (tid == 1) {
        float e = rowp[513];
        rowp[514] = e; rowp[515] = e; rowp[516] = e;
        rowp[517] = e; rowp[518] = e; rowp[519] = e;
    }
    FA[tid]       = make_float2(rowp[2 + 2 * tid],       rowp[2 + 2 * tid + 1]);
    FA[tid + 128] = make_float2(rowp[2 + 2 * (tid + 128)], rowp[2 + 2 * (tid + 128) + 1]);
    __syncthreads();

    // ---- 8-stage Stockham radix-2 FFT (256-pt complex), ping-pong FA/FB ----
    {
        float2* src = FA;
        float2* dst = FB;
        #pragma unroll
        for (int s = 1; s <= 8; ++s) {
            const int l = 1 << (s - 1);
            const int p = tid & (l - 1);
            const int i0 = 2 * tid - p;
            float sw, cw;
            sincosf(-(float)p * (PI_F / (float)l), &sw, &cw);
            float2 a = src[tid];
            float2 b = src[tid + 128];
            float tr = cw * b.x - sw * b.y;
            float ti = cw * b.y + sw * b.x;
            dst[i0]     = make_float2(a.x + tr, a.y + ti);
            dst[i0 + l] = make_float2(a.x - tr, a.y - ti);
            __syncthreads();
            float2* tmp = src; src = dst; dst = tmp;
        }
        // 8 stages (even) -> result back in FA, natural order
    }

    // ---- rfft unpack: thread j -> bins k = j+1 and k = j+129; amp = |F[k]| ----
    float v[2]; int id[2];
    #pragma unroll
    for (int q = 0; q < 2; ++q) {
        const int k = 1 + tid + 128 * q;
        float2 A = FA[k & 255];
        float2 Bv = FA[(256 - k) & 255];
        float Er = 0.5f * (A.x + Bv.x);
        float Ei = 0.5f * (A.y - Bv.y);
        float Or = 0.5f * (A.y + Bv.y);
        float Oi = 0.5f * (Bv.x - A.x);
        float sth, cth;
        sincosf((float)k * (PI_F / 256.0f), &sth, &cth);
        float Fr = Er + cth * Or + sth * Oi;
        float Fi = Ei + cth * Oi - sth * Or;
        v[q] = sqrtf(Fr * Fr + Fi * Fi);
        id[q] = k;
    }

    // ---- wave-local top-3 then cross-wave merge ----
    {
        const int wv = tid >> 6;
        float vals[3]; int idxs[3];
        #pragma unroll
        for (int kk = 0; kk < 3; ++kk) {
            float bv = v[0]; int bi = id[0];
            if (v[1] > bv || (v[1] == bv && id[1] < bi)) { bv = v[1]; bi = id[1]; }
            #pragma unroll
            for (int off = 32; off >= 1; off >>= 1) {
                float ov = __shfl_xor(bv, off, 64);
                int   oi = __shfl_xor(bi, off, 64);
                if (ov > bv || (ov == bv && oi < bi)) { bv = ov; bi = oi; }
            }
            vals[kk] = bv; idxs[kk] = bi;
            #pragma unroll
            for (int q = 0; q < 2; ++q)
                if (id[q] == bi) v[q] = -1e30f;
        }
        if ((tid & 63) == 0) {
            #pragma unroll
            for (int kk = 0; kk < 3; ++kk) {
                wtopS[wv * 3 + kk] = vals[kk];
                itopS[wv * 3 + kk] = idxs[kk];
            }
        }
    }
    __syncthreads();
    if (tid == 0) {
        float vv[6]; int ii[6];
        #pragma unroll
        for (int q = 0; q < 6; ++q) { vv[q] = wtopS[q]; ii[q] = itopS[q]; }
        float vals[3]; int idxs[3];
        #pragma unroll
        for (int kk = 0; kk < 3; ++kk) {
            float bv = vv[0]; int bi = ii[0];
            #pragma unroll
            for (int q = 1; q < 6; ++q)
                if (vv[q] > bv || (vv[q] == bv && ii[q] < bi)) { bv = vv[q]; bi = ii[q]; }
            vals[kk] = bv; idxs[kk] = bi;
            #pragma unroll
            for (int q = 0; q < 6; ++q)
                if (ii[q] == bi) vv[q] = -1e30f;
        }
        float m = fmaxf(vals[0], fmaxf(vals[1], vals[2]));
        float e0 = expf(vals[0] - m), e1 = expf(vals[1] - m), e2 = expf(vals[2] - m);
        float inv = 1.0f / (e0 + e1 + e2);
        bwS[0] = e0 * inv; bwS[1] = e1 * inv; bwS[2] = e2 * inv;
        #pragma unroll
        for (int kk = 0; kk < 3; ++kk) {
            int fi = idxs[kk];
            int P = T_ / fi;
            P = P < 32 ? 32 : (P > 512 ? 512 : P);
            int cyc = T_ / P;
            ipS[kk] = P; ipS[3 + kk] = cyc; ipS[6 + kk] = T_ - cyc * P;
        }
    }
    __syncthreads();

    // ---- fold + conv + pools + seq ----
    const int P0  = __builtin_amdgcn_readfirstlane(ipS[0]);
    const int P1  = __builtin_amdgcn_readfirstlane(ipS[1]);
    const int P2  = __builtin_amdgcn_readfirstlane(ipS[2]);
    const int cy0 = __builtin_amdgcn_readfirstlane(ipS[3]);
    const int cy1 = __builtin_amdgcn_readfirstlane(ipS[4]);
    const int cy2 = __builtin_amdgcn_readfirstlane(ipS[5]);
    const int bs0 = __builtin_amdgcn_readfirstlane(ipS[6]);
    const int bs1 = __builtin_amdgcn_readfirstlane(ipS[7]);
    const int bs2 = __builtin_amdgcn_readfirstlane(ipS[8]);
    const float bw0 = bwS[0], bw1 = bwS[1], bw2 = bwS[2];
    const float beff = WeffS[75], wr0 = WeffS[76], wr1 = WeffS[77],
                wr2 = WeffS[78], bres = WeffS[79];

    int maxP = P0 > P1 ? P0 : P1; maxP = maxP > P2 ? maxP : P2;
    const int Pk[3]   = {P0, P1, P2};
    const int cykA[3] = {cy0, cy1, cy2};
    const int bskA[3] = {bs0, bs1, bs2};
    const int woff = tid & 64;          // wave base within chunk

    #pragma unroll 1
    for (int pc = 0; pc < T_; pc += 128) {
        const int p = pc + tid;
        const int wb = __builtin_amdgcn_readfirstlane(pc + woff);
        if (wb >= maxP) {
            avg_out[r * T_ + p] = 0.f;
            max_out[r * T_ + p] = 0.f;
            seq_out[r * T_ + p] = 0.f;
            continue;
        }
        int c0 = (P0 > wb) ? cy0 : 0;
        int c1 = (P1 > wb) ? cy1 : 0;
        int c2 = (P2 > wb) ? cy2 : 0;
        int cymax = c0 > c1 ? c0 : c1; cymax = cymax > c2 ? cymax : c2;
        cymax = __builtin_amdgcn_readfirstlane(cymax);

        float zacc[CMAX_];
        #pragma unroll
        for (int i = 0; i < CMAX_; ++i) zacc[i] = beff;

        #pragma unroll 1
        for (int k = 0; k < 3; ++k) {
            const int P = Pk[k];
            if (wb >= P) continue;          // wave-uniform skip
            const int cy = cykA[k];
            const int bs = bskA[k];
            float Wk[5][5];
            #pragma unroll
            for (int i = 0; i < 5; ++i)
                #pragma unroll
                for (int j = 0; j < 5; ++j)
                    Wk[i][j] = WeffS[k * 25 + i * 5 + j];
            bool mdw[5];
            #pragma unroll
            for (int dw = -2; dw <= 2; ++dw)
                mdw[dw + 2] = ((unsigned)(p + dw) < (unsigned)P);
            const int abase = bs + p + 2;   // padded-index base
            #pragma unroll
            for (int hh = 0; hh < CMAX_; ++hh) {
                if (hh < cy) {              // lane-uniform guard
                    const int a0 = abase + hh * P;
                    float w[5];
                    #pragma unroll
                    for (int dw = -2; dw <= 2; ++dw) {
                        unsigned a = (unsigned)(a0 + dw);
                        a = a > 517u ? 517u : a;    // single clamp (halo handles low)
                        float t = rowp[a];
                        w[dw + 2] = mdw[dw + 2] ? t : 0.f;
                    }
                    #pragma unroll
                    for (int dh = -2; dh <= 2; ++dh) {
                        const int cc = hh - dh;     // compile-time
                        if (cc >= 0 && cc < CMAX_) {
                            #pragma unroll
                            for (int dw = 0; dw < 5; ++dw)
                                zacc[cc] = fmaf(Wk[dh + 2][dw], w[dw], zacc[cc]);
                        }
                    }
                }
            }
        }

        float avg_num = 0.f, den = 0.f, mx = -3.402823466e38f;
        int anyv = 0;
        const int pl0 = (p < P0), pl1 = (p < P1), pl2 = (p < P2);
        #pragma unroll
        for (int cc = 0; cc < CMAX_; ++cc) {
            if (cc < cymax) {               // uniform guard
                int m0 = (cc < cy0) & pl0;
                int m1 = (cc < cy1) & pl1;
                int m2 = (cc < cy2) & pl2;
                unsigned a0 = (unsigned)(bs0 + cc * P0 + p); a0 = a0 > 511u ? 511u : a0;
                unsigned a1 = (unsigned)(bs1 + cc * P1 + p); a1 = a1 > 511u ? 511u : a1;
                unsigned a2 = (unsigned)(bs2 + cc * P2 + p); a2 = a2 > 511u ? 511u : a2;
                float x0v = m0 ? rowp[2 + a0] : 0.f;
                float x1v = m1 ? rowp[2 + a1] : 0.f;
                float x2v = m2 ? rowp[2 + a2] : 0.f;
                float res = fmaf(wr0, x0v, fmaf(wr1, x1v, fmaf(wr2, x2v, bres)));
                float z = gelu_exact(zacc[cc]) + res;
                int mm = m0 | m1 | m2;
                float cm = mm ? 1.f : 0.f;
                avg_num += z * cm;
                den += cm;
                mx = mm ? fmaxf(mx, z) : mx;
                anyv |= mm;
            }
        }
        float avg = avg_num / (den + FEPS);
        float mpool = anyv ? mx : 0.f;

        float seq = 0.f;
        #pragma unroll 1
        for (int k = 0; k < 3; ++k) {
            const int P = Pk[k];
            if (wb >= P) continue;
            const int cy = cykA[k];
            const int bs = bskA[k];
            float s = 0.f;
            for (int c2i = 0; c2i < cy; ++c2i) {
                unsigned a = (unsigned)(bs + c2i * P + p); a = a > 511u ? 511u : a;
                s += ((p < P) ? rowp[2 + a] : 0.f);
            }
            float brk = (p < P) ? s / ((float)cy + FEPS) : 0.f;
            float bwk = (k == 0) ? bw0 : (k == 1 ? bw1 : bw2);
            seq = fmaf(bwk, brk, seq);
        }

        avg_out[r * T_ + p] = avg;
        max_out[r * T_ + p] = mpool;
        seq_out[r * T_ + p] = seq;
    }
}

// ---------- fuse GEMM + gelu ----------
// grid (8 t-tiles, 32 b), 256 threads, 64o x 64t tile, 4x4 micro.
__global__ __launch_bounds__(256) void fuse_kernel(
    const float* __restrict__ avgb, const float* __restrict__ maxb,
    const float* __restrict__ seqb,
    const float* __restrict__ wf, const float* __restrict__ bfu,
    float* __restrict__ out)
{
    __shared__ float wT[64][68];    // wT[c][o]
    __shared__ float Bt[64][68];    // Bt[c][t]
    const int tid = threadIdx.x;
    const int b = blockIdx.y;
    const int tt0 = blockIdx.x * 64;
    const int og = tid >> 4;
    const int tg = tid & 15;
    const int o0 = og * 4;
    const int t0 = tg * 4;

    float acc[4][4];
    #pragma unroll
    for (int i = 0; i < 4; ++i)
        #pragma unroll
        for (int j = 0; j < 4; ++j) acc[i][j] = 0.f;

    const float* srcs[3] = {avgb, maxb, seqb};
    for (int g = 0; g < 3; ++g) {
        const float* __restrict__ src = srcs[g];
        #pragma unroll
        for (int it = 0; it < 4; ++it) {
            int idx = tid + it * 256;
            int c = idx >> 4, t4 = idx & 15;
            float4 vv = reinterpret_cast<const float4*>(
                            &src[(b * 64 + c) * 512 + tt0])[t4];
            *reinterpret_cast<float4*>(&Bt[c][t4 * 4]) = vv;
        }
        for (int i = tid; i < 64 * 64; i += 256) {
            int c = i & 63, o = i >> 6;
            wT[c][o] = wf[o * 192 + g * 64 + c];
        }
        __syncthreads();
        for (int c = 0; c < 64; ++c) {
            float4 wv = *reinterpret_cast<const float4*>(&wT[c][o0]);
            float4 bv = *reinterpret_cast<const float4*>(&Bt[c][t0]);
            const float wa[4] = {wv.x, wv.y, wv.z, wv.w};
            const float ba[4] = {bv.x, bv.y, bv.z, bv.w};
            #pragma unroll
            for (int i = 0; i < 4; ++i)
                #pragma unroll
                for (int j = 0; j < 4; ++j)
                    acc[i][j] = fmaf(wa[i], ba[j], acc[i][j]);
        }
        __syncthreads();
    }
    #pragma unroll
    for (int i = 0; i < 4; ++i) {
        float bias = bfu[o0 + i];
        float4 o4;
        o4.x = gelu_exact(acc[i][0] + bias);
        o4.y = gelu_exact(acc[i][1] + bias);
        o4.z = gelu_exact(acc[i][2] + bias);
        o4.w = gelu_exact(acc[i][3] + bias);
        *reinterpret_cast<float4*>(
            &out[(b * 64 + (o0 + i)) * 512 + tt0 + t0]) = o4;
    }
}

extern "C" void kernel_launch(void* const* d_in, const int* in_sizes, int n_in,
                              void* d_out, int out_size, void* d_ws, size_t ws_size,
                              hipStream_t stream) {
    const float* feat = (const float*)d_in[0];
    const float* w0  = (const float*)d_in[1];
    const float* b0  = (const float*)d_in[2];
    const float* w1  = (const float*)d_in[3];
    const float* b1  = (const float*)d_in[4];
    const float* w2  = (const float*)d_in[5];
    const float* b2  = (const float*)d_in[6];
    const float* wpj = (const float*)d_in[7];
    const float* bpj = (const float*)d_in[8];
    const float* wr  = (const float*)d_in[9];
    const float* br  = (const float*)d_in[10];
    const float* wf  = (const float*)d_in[11];
    const float* bfu = (const float*)d_in[12];

    float* ws = (float*)d_ws;
    float* avgb = ws;
    float* maxb = ws + (size_t)NROWS * T_;
    float* seqb = ws + 2 * (size_t)NROWS * T_;

    mono_kernel<<<NROWS, 128, 0, stream>>>(feat, w0, b0, w1, b1, w2, b2,
                                           wpj, bpj, wr, br, avgb, maxb, seqb);
    fuse_kernel<<<dim3(8, 32), 256, 0, stream>>>(avgb, maxb, seqb, wf, bfu,
                                                 (float*)d_out);
}